// Round 1
// baseline (16.695 us; speedup 1.0000x reference)
//
#include <hip/hip_runtime.h>

#define S_LEN 2048
#define H_NUM 8
#define D_DIM 64
#define W_WIN 32
#define TS 64
#define ROWS (TS + W_WIN - 1)   // 95
#define PADK 68                 // floats per LDS row: 16B-aligned stride, breaks stride-64 bank pathology

__global__ __launch_bounds__(256) void swa_gated_kernel(
    const float* __restrict__ q, const float* __restrict__ k,
    const float* __restrict__ v, const float* __restrict__ a,
    const float* __restrict__ bgate, float* __restrict__ out)
{
    __shared__ __align__(16) float k_lds[ROWS][PADK];
    __shared__ __align__(16) float v_lds[ROWS][PADK];
    __shared__ float w_lds[TS][W_WIN + 1];
    __shared__ float a_lds[ROWS + 1];
    __shared__ float b_lds[TS];

    const int tid  = threadIdx.x;
    const int bid  = blockIdx.x;
    const int tile = bid & 31;          // S/TS = 32 tiles
    const int h    = (bid >> 5) & 7;    // 8 heads
    const int bb   = bid >> 8;          // batch
    const int s0   = tile * TS;
    const size_t HD = (size_t)H_NUM * D_DIM;   // 512

    // ---- stage k/v rows [s0-31, s0+TS) into LDS (float4, coalesced) ----
    for (int idx = tid; idx < ROWS * 16; idx += 256) {
        int r  = idx >> 4;
        int c4 = idx & 15;
        int seq = s0 - (W_WIN - 1) + r;
        int seqc = seq < 0 ? 0 : seq;   // clamped; invalid masked later
        size_t base = ((size_t)(bb * S_LEN + seqc)) * HD + (size_t)h * D_DIM + c4 * 4;
        float4 kv = *(const float4*)(k + base);
        float4 vv = *(const float4*)(v + base);
        *(float4*)&k_lds[r][c4 * 4] = kv;
        *(float4*)&v_lds[r][c4 * 4] = vv;
    }
    for (int r = tid; r < ROWS; r += 256) {
        int seq = s0 - (W_WIN - 1) + r;
        int seqc = seq < 0 ? 0 : seq;
        a_lds[r] = a[((size_t)(bb * S_LEN + seqc)) * H_NUM + h];
    }
    if (tid < TS) {
        b_lds[tid] = bgate[((size_t)(bb * S_LEN + s0 + tid)) * H_NUM + h];
    }
    __syncthreads();

    // ---- score phase: thread -> (query qi, window positions wb+4j) ----
    {
        const int qi = tid >> 2;
        const int wb = tid & 3;
        const float* qrow = q + ((size_t)(bb * S_LEN + s0 + qi)) * HD + (size_t)h * D_DIM;
        float acc[8] = {0.f,0.f,0.f,0.f,0.f,0.f,0.f,0.f};
        #pragma unroll
        for (int d4 = 0; d4 < 16; ++d4) {
            float4 qv = *(const float4*)(qrow + d4 * 4);
            #pragma unroll
            for (int j = 0; j < 8; ++j) {
                int row = qi + wb + 4 * j;   // seq = s0-31+(qi+w)
                float4 kv = *(const float4*)&k_lds[row][d4 * 4];
                acc[j] += qv.x * kv.x + qv.y * kv.y + qv.z * kv.z + qv.w * kv.w;
            }
        }
        const float scale = 0.125f;   // 1/sqrt(64)
        const float bg = b_lds[qi];
        #pragma unroll
        for (int j = 0; j < 8; ++j) {
            int w   = wb + 4 * j;
            int row = qi + w;
            int seq = s0 + qi - (W_WIN - 1) + w;
            float gate = 1.0f / (1.0f + __expf(-(a_lds[row] * bg)));
            float wt = acc[j] * scale * gate;
            w_lds[qi][w] = (seq >= 0) ? wt : 0.0f;
        }
    }
    __syncthreads();

    // ---- PV phase: thread -> (query qi, 16-dim chunk db) ----
    {
        const int qi = tid >> 2;
        const int db = tid & 3;
        float o[16];
        #pragma unroll
        for (int i = 0; i < 16; ++i) o[i] = 0.f;
        #pragma unroll
        for (int w = 0; w < W_WIN; ++w) {
            float wt = w_lds[qi][w];
            int row = qi + w;
            #pragma unroll
            for (int i4 = 0; i4 < 4; ++i4) {
                float4 vv = *(const float4*)&v_lds[row][db * 16 + i4 * 4];
                o[i4*4+0] += wt * vv.x;
                o[i4*4+1] += wt * vv.y;
                o[i4*4+2] += wt * vv.z;
                o[i4*4+3] += wt * vv.w;
            }
        }
        float* orow = out + ((size_t)(bb * S_LEN + s0 + qi)) * HD + (size_t)h * D_DIM + db * 16;
        #pragma unroll
        for (int i4 = 0; i4 < 4; ++i4) {
            *(float4*)(orow + i4 * 4) =
                make_float4(o[i4*4+0], o[i4*4+1], o[i4*4+2], o[i4*4+3]);
        }
    }
}

extern "C" void kernel_launch(void* const* d_in, const int* in_sizes, int n_in,
                              void* d_out, int out_size, void* d_ws, size_t ws_size,
                              hipStream_t stream) {
    const float* q  = (const float*)d_in[0];
    const float* k  = (const float*)d_in[1];
    const float* v  = (const float*)d_in[2];
    const float* a  = (const float*)d_in[3];
    const float* bg = (const float*)d_in[4];
    float* out = (float*)d_out;

    dim3 grid(2 /*B*/ * H_NUM * (S_LEN / TS));   // 512 blocks
    swa_gated_kernel<<<grid, 256, 0, stream>>>(q, k, v, a, bg, out);
}